// Round 13
// baseline (344.643 us; speedup 1.0000x reference)
//
#include <hip/hip_runtime.h>

#define N_IN   128
#define DD     256
#define KSEL   4096
#define NBATCH 8
#define NGROUP 16
#define HSLOTS 4
#define K1_CPB 250
#define K1_ROWS 400
#define CCH    8            // collect chunks per group
#define CSPAN  12500        // RR / CCH
#define SUBCAP 4096u        // packed-candidate cap per (group,chunk)
#define CAPG   (CCH*4096)
#define WCH    13           // write_gather chunks per group (13*8192 >= 100000)
#define USLICE 16           // update slices per group

__device__ __forceinline__ unsigned keyOf(float s){
    unsigned b = __float_as_uint(s);
    return (b & 0x80000000u) ? ~b : (b | 0x80000000u);
}

__device__ __forceinline__ float4 blend4(float4 o, float4 u){
    o.x = (o.x + u.x)*0.5f; o.y = (o.y + u.y)*0.5f;
    o.z = (o.z + u.z)*0.5f; o.w = (o.w + u.w)*0.5f;
    return o;
}

// ---------------------------------------------------------------------------
// Kernel 0: zero gDone | gListCnt | gHist.
// ---------------------------------------------------------------------------
__global__ __launch_bounds__(256) void zero_kernel(uint4* __restrict__ p, int n16){
    const int i = blockIdx.x * 256 + threadIdx.x;
    if (i < n16) p[i] = uint4{0u,0u,0u,0u};
}

// ---------------------------------------------------------------------------
// Kernel 1: scores + fused 11-bit histogram + x->out copy. (proven verbatim)
// ---------------------------------------------------------------------------
__global__ __launch_bounds__(256) void scores_hist_copy_kernel(
        const float* __restrict__ x, const float* __restrict__ W_fr,
        const float* __restrict__ b_fr, unsigned* __restrict__ keys,
        unsigned* __restrict__ gHist, float* __restrict__ out, int N, int R)
{
    const int b   = blockIdx.x / K1_CPB;
    const int c   = blockIdx.x % K1_CPB;
    const int rbase = b * R + c * K1_ROWS;
    const int tid = threadIdx.x;
    const int wave = tid >> 6, lane = tid & 63;

    __shared__ unsigned h0[2048], h1[2048];
    for (int i = tid; i < 2048; i += 256){ h0[i] = 0u; h1[i] = 0u; }
    __syncthreads();

    const int f = 4 * (lane & 31);
    const float w00 = W_fr[(f+0)*2+0], w01 = W_fr[(f+0)*2+1];
    const float w10 = W_fr[(f+1)*2+0], w11 = W_fr[(f+1)*2+1];
    const float w20 = W_fr[(f+2)*2+0], w21 = W_fr[(f+2)*2+1];
    const float w30 = W_fr[(f+3)*2+0], w31 = W_fr[(f+3)*2+1];
    const float bf0 = b_fr[0], bf1 = b_fr[1];

    for (int it = 0; it < K1_ROWS/8; ++it){
        const int r0 = rbase + it*8 + wave*2;
        const size_t base = (size_t)r0 * N_IN + 4*lane;
        const float4 xv = *reinterpret_cast<const float4*>(x + base);
        *reinterpret_cast<float4*>(out + base) = xv;       // fused copy
        double p0 = (double)xv.x*w00 + (double)xv.y*w10 + (double)xv.z*w20 + (double)xv.w*w30;
        double p1 = (double)xv.x*w01 + (double)xv.y*w11 + (double)xv.z*w21 + (double)xv.w*w31;
        #pragma unroll
        for (int off = 16; off; off >>= 1){
            p0 += __shfl_xor(p0, off, 32);
            p1 += __shfl_xor(p1, off, 32);
        }
        const unsigned k0 = keyOf((float)(p0 + bf0));
        const unsigned k1 = keyOf((float)(p1 + bf1));
        const int r = r0 + (lane >> 5);
        if ((lane & 31) == 0){ keys[r]     = k0; atomicAdd(&h0[k0 >> 21], 1u); }
        if ((lane & 31) == 1){ keys[N + r] = k1; atomicAdd(&h1[k1 >> 21], 1u); }
    }
    __syncthreads();
    const int slot = c & (HSLOTS-1);
    unsigned* gh0 = gHist + ((size_t)(2*b)   * HSLOTS + slot) * 2048;
    unsigned* gh1 = gHist + ((size_t)(2*b+1) * HSLOTS + slot) * 2048;
    for (int bin = tid; bin < 2048; bin += 256){
        const unsigned s0 = h0[bin], s1 = h1[bin];
        if (s0) atomicAdd(&gh0[bin], s0);
        if (s1) atomicAdd(&gh1[bin], s1);
    }
}

// ---------------------------------------------------------------------------
// Kernel 2: packed candidate collect (R12-proven) + per-group last-block
// refine over SEQUENTIAL packed candidates (R7-proven gDone pattern).
// 16 groups x 8 chunks x 1024 threads.
// ---------------------------------------------------------------------------
__global__ __launch_bounds__(1024) void collect_refine_kernel(
        const unsigned* __restrict__ keys, const unsigned* __restrict__ gHist,
        unsigned* __restrict__ gCandCnt, unsigned long long* __restrict__ cand,
        unsigned* __restrict__ gParams, unsigned* __restrict__ gDone,
        int N, int R)
{
    const int g = blockIdx.x >> 3, ch = blockIdx.x & 7;
    const int b = g >> 1, v = g & 1;
    const unsigned* kk = keys + (size_t)v * N + (size_t)b * R;
    const int tid = threadIdx.x, wv = tid >> 6, lane = tid & 63;

    __shared__ unsigned lh[2048];
    __shared__ unsigned coarse[32];
    __shared__ unsigned sB[2];
    __shared__ unsigned wcnt[16];
    __shared__ unsigned sLoc;
    __shared__ unsigned nccs[CCH];
    __shared__ unsigned sOld;

    // ---- (a) redundant per-group threshold ----
    {
        const unsigned* gh = gHist + (size_t)g * HSLOTS * 2048;
        for (int bin = tid; bin < 2048; bin += 1024){
            unsigned ss = 0;
            #pragma unroll
            for (int sl = 0; sl < HSLOTS; ++sl) ss += gh[sl*2048 + bin];
            lh[bin] = ss;
        }
        __syncthreads();
        if (tid < 32){ unsigned ss = 0; for (int j = 0; j < 64; ++j) ss += lh[tid*64+j]; coarse[tid] = ss; }
        __syncthreads();
        if (tid == 0){
            unsigned kneed = KSEL, cum = 0; int cb = 31;
            for (; cb > 0; --cb){ if (cum + coarse[cb] >= kneed) break; cum += coarse[cb]; }
            int bin = cb*64 + 63;
            for (; bin > cb*64; --bin){ if (cum + lh[bin] >= kneed) break; cum += lh[bin]; }
            sB[0] = (unsigned)bin; sB[1] = kneed - cum;
            sLoc = 0u;
        }
        __syncthreads();
    }
    const unsigned B1 = sB[0], kneed1 = sB[1];

    // ---- (b) scan own chunk: packed (key,idx) candidates ----
    {
        unsigned long long* cd = cand + (size_t)g * CAPG + (size_t)ch * 4096;
        const int lo = ch * CSPAN, hi = min(R, lo + CSPAN);
        for (int i0 = lo; i0 < hi; i0 += 1024){
            const int i = i0 + tid;
            const bool pred = (i < hi) && ((kk[i] >> 21) == B1);
            const unsigned u = pred ? kk[i] : 0u;
            unsigned long long m = __ballot(pred);
            if (lane == 0) wcnt[wv] = (unsigned)__popcll(m);
            __syncthreads();
            unsigned pre = sLoc, tot = 0;
            #pragma unroll
            for (int w = 0; w < 16; ++w){ const unsigned cc = wcnt[w]; if (w < wv) pre += cc; tot += cc; }
            if (pred){
                const unsigned p = pre + (unsigned)__popcll(m & ((1ULL << lane) - 1ULL));
                if (p < SUBCAP) cd[p] = ((unsigned long long)u << 32) | (unsigned)i;
            }
            __syncthreads();
            if (tid == 0) sLoc += tot;
            __syncthreads();
        }
        if (tid == 0) gCandCnt[g*CCH + ch] = min(sLoc, SUBCAP);
    }

    // ---- (c) last chunk of this group refines (sequential packed reads) ----
    __threadfence();
    if (tid == 0) sOld = atomicAdd(&gDone[g*16], 1u);
    __syncthreads();
    if (sOld != CCH-1) return;
    __threadfence();   // acquire

    if (tid < CCH) nccs[tid] = gCandCnt[g*CCH + tid];
    __syncthreads();
    const unsigned long long* cd0 = cand + (size_t)g * CAPG;

    // phase B: bits 20..10 (descending)
    for (int i = tid; i < 2048; i += 1024) lh[i] = 0u;
    __syncthreads();
    for (int c2 = 0; c2 < CCH; ++c2){
        const int n = (int)nccs[c2];
        const unsigned long long* cdp = cd0 + (size_t)c2*4096;
        for (int i = tid; i < n; i += 1024)
            atomicAdd(&lh[((unsigned)(cdp[i] >> 32) >> 10) & 0x7FFu], 1u);
    }
    __syncthreads();
    if (tid < 32){ unsigned ss = 0; for (int j = 0; j < 64; ++j) ss += lh[tid*64+j]; coarse[tid] = ss; }
    __syncthreads();
    if (tid == 0){
        unsigned kneed = kneed1, cum = 0; int cb = 31;
        for (; cb > 0; --cb){ if (cum + coarse[cb] >= kneed) break; cum += coarse[cb]; }
        int bin = cb*64 + 63;
        for (; bin > cb*64; --bin){ if (cum + lh[bin] >= kneed) break; cum += lh[bin]; }
        sB[0] = (unsigned)bin; sB[1] = kneed - cum;
    }
    __syncthreads();
    const unsigned B2 = sB[0], kneed2 = sB[1];
    const unsigned top22 = (B1 << 11) | B2;
    __syncthreads();

    // phase C: low 10 bits (descending)
    for (int i = tid; i < 1024; i += 1024) lh[i] = 0u;
    __syncthreads();
    for (int c2 = 0; c2 < CCH; ++c2){
        const int n = (int)nccs[c2];
        const unsigned long long* cdp = cd0 + (size_t)c2*4096;
        for (int i = tid; i < n; i += 1024){
            const unsigned u = (unsigned)(cdp[i] >> 32);
            if ((u >> 10) == top22) atomicAdd(&lh[u & 0x3FFu], 1u);
        }
    }
    __syncthreads();
    if (tid < 32){ unsigned ss = 0; for (int j = 0; j < 32; ++j) ss += lh[tid*32+j]; coarse[tid] = ss; }
    __syncthreads();
    if (tid == 0){
        unsigned kneed = kneed2, cum = 0; int cb = 31;
        for (; cb > 0; --cb){ if (cum + coarse[cb] >= kneed) break; cum += coarse[cb]; }
        int bin = cb*32 + 31;
        for (; bin > cb*32; --bin){ if (cum + lh[bin] >= kneed) break; cum += lh[bin]; }
        sB[0] = (unsigned)bin; sB[1] = kneed - cum;
    }
    __syncthreads();
    const unsigned B3 = sB[0], take_eq = sB[1];
    const unsigned utar = (B1 << 21) | (B2 << 10) | B3;
    __syncthreads();

    // phase T1: idx>>7 among ties (ascending)
    for (int i = tid; i < 1024; i += 1024) lh[i] = 0u;
    __syncthreads();
    for (int c2 = 0; c2 < CCH; ++c2){
        const int n = (int)nccs[c2];
        const unsigned long long* cdp = cd0 + (size_t)c2*4096;
        for (int i = tid; i < n; i += 1024){
            const unsigned long long e = cdp[i];
            if ((unsigned)(e >> 32) == utar) atomicAdd(&lh[((unsigned)e) >> 7], 1u);
        }
    }
    __syncthreads();
    if (tid < 32){ unsigned ss = 0; for (int j = 0; j < 32; ++j) ss += lh[tid*32+j]; coarse[tid] = ss; }
    __syncthreads();
    if (tid == 0){
        unsigned need = take_eq, cum = 0; int cb = 0;
        for (; cb < 31; ++cb){ if (cum + coarse[cb] >= need) break; cum += coarse[cb]; }
        int bin = cb*32;
        for (; bin < cb*32+31; ++bin){ if (cum + lh[bin] >= need) break; cum += lh[bin]; }
        sB[0] = (unsigned)bin; sB[1] = need - cum;
    }
    __syncthreads();
    const unsigned cb7 = sB[0], rem = sB[1];
    __syncthreads();

    // phase T2: low 7 index bits (ascending)
    if (tid < 128) lh[tid] = 0u;
    __syncthreads();
    for (int c2 = 0; c2 < CCH; ++c2){
        const int n = (int)nccs[c2];
        const unsigned long long* cdp = cd0 + (size_t)c2*4096;
        for (int i = tid; i < n; i += 1024){
            const unsigned long long e = cdp[i];
            const unsigned ix = (unsigned)e;
            if ((unsigned)(e >> 32) == utar && (ix >> 7) == cb7) atomicAdd(&lh[ix & 127], 1u);
        }
    }
    __syncthreads();
    if (tid == 0){
        unsigned need = rem, cum = 0; int p = 0;
        for (; p < 127; ++p){ if (cum + lh[p] >= need) break; cum += lh[p]; }
        gParams[g*8+2] = utar;
        gParams[g*8+3] = cb7*128 + (unsigned)p;   // T
    }
}

// ---------------------------------------------------------------------------
// Kernel 3: lean list builder (R12-proven) + fused fp64 gather of this
// block's selected rows (reads back its own L2-hot list range).
// 16 groups x 13 chunks x 1024 threads.
// ---------------------------------------------------------------------------
__global__ __launch_bounds__(1024) void write_gather_kernel(
        const unsigned* __restrict__ keys, const unsigned* __restrict__ gParams,
        const float* __restrict__ x, int* __restrict__ lists,
        unsigned* __restrict__ gListCnt, double* __restrict__ part,
        int N, int R)
{
    const int g = blockIdx.x / WCH, c = blockIdx.x % WCH;
    const int b = g >> 1, v = g & 1;
    const unsigned* kk = keys + (size_t)v * N + (size_t)b * R;
    int* lst = lists + g * KSEL;
    const unsigned utar = gParams[g*8+2];
    const int T = (int)gParams[g*8+3];
    const int tid = threadIdx.x, wave = tid >> 6, lane = tid & 63;
    const int i0 = c * 8192;

    bool pr[8];
    #pragma unroll
    for (int j = 0; j < 8; ++j){
        const int i = i0 + j*1024 + tid;
        const unsigned u = (i < R) ? kk[i] : 0u;
        pr[j] = (i < R) && (u > utar || (u == utar && i <= T));
    }
    __shared__ unsigned wc[8][16];
    __shared__ unsigned ec[8][16];
    __shared__ unsigned sBase;
    __shared__ double red[32][128];
    #pragma unroll
    for (int j = 0; j < 8; ++j){
        unsigned long long m = __ballot(pr[j]);
        if (lane == 0) wc[j][wave] = (unsigned)__popcll(m);
    }
    __syncthreads();
    if (tid == 0){
        unsigned run = 0;
        for (int j = 0; j < 8; ++j)
            for (int w = 0; w < 16; ++w){ ec[j][w] = run; run += wc[j][w]; }
        sBase = run ? atomicAdd(&gListCnt[g*16], run) : 0u;
        wc[0][0] = run;   // reuse as run broadcast
    }
    __syncthreads();
    const unsigned base = sBase;
    const unsigned run = wc[0][0];
    #pragma unroll
    for (int j = 0; j < 8; ++j){
        unsigned long long m = __ballot(pr[j]);
        if (pr[j])
            lst[base + ec[j][wave] + (unsigned)__popcll(m & ((1ULL << lane) - 1ULL))] = i0 + j*1024 + tid;
    }
    __syncthreads();   // block-level visibility of our own global writes

    // ---- fused gather: this block's selected rows -> fp64 partial ----
    const float* xb = x + (size_t)b * R * N_IN;
    const int slot = tid >> 5;            // 32 row slots
    const int c4 = (tid & 31) * 4;        // 32 lanes x float4
    double a0 = 0.0, a1 = 0.0, a2 = 0.0, a3 = 0.0;
    for (unsigned rr = slot; rr < run; rr += 32){
        const float4 xv = *reinterpret_cast<const float4*>(
            xb + (size_t)lst[base + rr] * N_IN + c4);
        a0 += xv.x; a1 += xv.y; a2 += xv.z; a3 += xv.w;
    }
    red[slot][c4+0] = a0; red[slot][c4+1] = a1;
    red[slot][c4+2] = a2; red[slot][c4+3] = a3;
    __syncthreads();
    #pragma unroll
    for (int st = 16; st >= 1; st >>= 1){
        if (slot < st){
            #pragma unroll
            for (int k = 0; k < 4; ++k)
                red[slot][c4+k] += red[slot+st][c4+k];
        }
        __syncthreads();
    }
    if (slot == 0){
        double* pp = part + ((size_t)g * WCH + c) * N_IN;
        pp[c4+0] = red[0][c4+0]; pp[c4+1] = red[0][c4+1];
        pp[c4+2] = red[0][c4+2]; pp[c4+3] = red[0][c4+3];
    }
}

// ---------------------------------------------------------------------------
// Kernel 4: redundant fp64 MLP per block + sparse blend with key-probe dedup.
// 16 groups x 16 slices x 256 threads. (R7-proven; 13 part slots)
// ---------------------------------------------------------------------------
__global__ __launch_bounds__(256) void update_mlp_kernel(
        const float* __restrict__ x, const unsigned* __restrict__ keys,
        const int* __restrict__ lists, const double* __restrict__ part,
        const unsigned* __restrict__ gParams,
        const float* __restrict__ W1, const float* __restrict__ b1,
        const float* __restrict__ W2, const float* __restrict__ b2,
        float* __restrict__ out, int N, int R)
{
    const int g = blockIdx.x >> 4, sl = blockIdx.x & (USLICE-1);
    const int b = g >> 1, v = g & 1;
    const int tid = threadIdx.x;

    __shared__ __align__(16) float inv[DD];
    __shared__ __align__(16) float h1s[DD];
    __shared__ __align__(16) float uu[DD];

    {
        const int g2 = b*2 + (tid >> 7);
        const int fcol = tid & 127;
        double ssum = 0.0;
        for (int cc = 0; cc < WCH; ++cc) ssum += part[((size_t)g2 * WCH + cc) * N_IN + fcol];
        inv[tid] = (float)(ssum / (double)KSEL);
    }
    __syncthreads();
    {
        double q0=0, q1=0, q2=0, q3=0;
        for (int i = 0; i < DD; i += 4){
            q0 += (double)inv[i+0] * (double)W1[(i+0)*DD + tid];
            q1 += (double)inv[i+1] * (double)W1[(i+1)*DD + tid];
            q2 += (double)inv[i+2] * (double)W1[(i+2)*DD + tid];
            q3 += (double)inv[i+3] * (double)W1[(i+3)*DD + tid];
        }
        h1s[tid] = fmaxf((float)(((q0+q1)+(q2+q3)) + (double)b1[tid]), 0.0f);
    }
    __syncthreads();
    {
        double q0=0, q1=0, q2=0, q3=0;
        for (int i = 0; i < DD; i += 4){
            q0 += (double)h1s[i+0] * (double)W2[(i+0)*DD + tid];
            q1 += (double)h1s[i+1] * (double)W2[(i+1)*DD + tid];
            q2 += (double)h1s[i+2] * (double)W2[(i+2)*DD + tid];
            q3 += (double)h1s[i+3] * (double)W2[(i+3)*DD + tid];
        }
        uu[tid] = (float)(((q0+q1)+(q2+q3)) + (double)b2[tid]);
    }
    __syncthreads();

    const int wave = tid >> 6, lane = tid & 63;
    const int half = lane >> 5;
    const int c4 = (lane & 31) * 4;
    const int* lst = lists + g * KSEL + sl * (KSEL/USLICE);
    const unsigned* k0p = keys + (size_t)b * R;
    const unsigned* k1p = keys + (size_t)N + (size_t)b * R;
    const unsigned utar0 = gParams[(b*2+0)*8+2]; const int T0  = (int)gParams[(b*2+0)*8+3];
    const unsigned utar1 = gParams[(b*2+1)*8+2]; const int T1v = (int)gParams[(b*2+1)*8+3];
    const float4 u0 = *reinterpret_cast<const float4*>(&uu[c4]);
    const float4 u1 = *reinterpret_cast<const float4*>(&uu[128 + c4]);
    const size_t rowBase = (size_t)b * R;

    for (int e = wave*2 + half; e < KSEL/USLICE; e += 8){
        const int row = lst[e];
        if (v == 1){
            const unsigned uk0 = k0p[row];
            if (uk0 > utar0 || (uk0 == utar0 && row <= T0)) continue;  // v0 pass handles
        }
        const size_t base = (rowBase + row) * N_IN + c4;
        float4 o = *reinterpret_cast<const float4*>(x + base);
        if (v == 0){
            o = blend4(o, u0);
            const unsigned uk1 = k1p[row];
            if (uk1 > utar1 || (uk1 == utar1 && row <= T1v)) o = blend4(o, u1);
        } else {
            o = blend4(o, u1);
        }
        *reinterpret_cast<float4*>(out + base) = o;
    }
}

extern "C" void kernel_launch(void* const* d_in, const int* in_sizes, int n_in_cnt,
                              void* d_out, int out_size, void* d_ws, size_t ws_size,
                              hipStream_t stream)
{
    const float* x    = (const float*)d_in[0];
    const float* W_fr = (const float*)d_in[1];
    const float* b_fr = (const float*)d_in[2];
    const float* W1   = (const float*)d_in[3];
    const float* b1   = (const float*)d_in[4];
    const float* W2   = (const float*)d_in[5];
    const float* b2   = (const float*)d_in[6];
    float* out = (float*)d_out;
    const int N = in_sizes[0] / N_IN;   // 800000
    const int R = N / NBATCH;           // 100000

    char* ws = (char*)d_ws;
    size_t off = 0;
    auto alloc = [&](size_t bytes) -> void* {
        void* p = ws + off;
        off = (off + bytes + 255) & ~(size_t)255;
        return p;
    };
    int*                lists   = (int*)               alloc((size_t)NGROUP * KSEL * 4);
    double*             part    = (double*)            alloc((size_t)NGROUP * WCH * N_IN * 8);
    unsigned long long* cand    = (unsigned long long*)alloc((size_t)NGROUP * CAPG * 8);
    unsigned*           keys    = (unsigned*)          alloc((size_t)2 * N * 4);
    unsigned*           gParams = (unsigned*)          alloc((size_t)NGROUP * 8 * 4);
    unsigned*           gCandCnt= (unsigned*)          alloc((size_t)NGROUP * CCH * 4);

    // zeroed region: gDone(16x16) | gListCnt(16x16) | gHist(16 x HSLOTS x 2048)
    const size_t zrUints = 16*16 + 16*16 + (size_t)NGROUP * HSLOTS * 2048;
    unsigned* zr = (unsigned*)alloc(zrUints * 4);
    unsigned* gDone    = zr;
    unsigned* gListCnt = zr + 16*16;
    unsigned* gHist    = zr + 16*16 + 16*16;

    const int n16 = (int)((zrUints * 4 + 15) / 16);
    zero_kernel<<<dim3((n16 + 255)/256), dim3(256), 0, stream>>>((uint4*)zr, n16);
    scores_hist_copy_kernel<<<dim3(NBATCH*K1_CPB), dim3(256), 0, stream>>>(
        x, W_fr, b_fr, keys, gHist, out, N, R);
    collect_refine_kernel<<<dim3(NGROUP*CCH), dim3(1024), 0, stream>>>(
        keys, gHist, gCandCnt, cand, gParams, gDone, N, R);
    write_gather_kernel<<<dim3(NGROUP*WCH), dim3(1024), 0, stream>>>(
        keys, gParams, x, lists, gListCnt, part, N, R);
    update_mlp_kernel<<<dim3(NGROUP*USLICE), dim3(256), 0, stream>>>(
        x, keys, lists, part, gParams, W1, b1, W2, b2, out, N, R);
}

// Round 14
// 338.898 us; speedup vs baseline: 1.0170x; 1.0170x over previous
//
#include <hip/hip_runtime.h>

#define N_IN   128
#define DD     256
#define KSEL   4096
#define NBATCH 8
#define NGROUP 16
#define HSLOTS 4
#define K1_CPB 250
#define K1_ROWS 400
#define CCH    8            // collect chunks per group
#define CSPAN  12500        // RR / CCH
#define SUBCAP 4096u        // packed-candidate cap per (group,chunk)
#define CAPG   (CCH*4096)
#define WCH    13           // write chunks per group (13*8192 >= 100000)
#define VCH    64           // virt_partial chunks per group (part slots)
#define USLICE 16           // update slices per group

__device__ __forceinline__ unsigned keyOf(float s){
    unsigned b = __float_as_uint(s);
    return (b & 0x80000000u) ? ~b : (b | 0x80000000u);
}

__device__ __forceinline__ float4 blend4(float4 o, float4 u){
    o.x = (o.x + u.x)*0.5f; o.y = (o.y + u.y)*0.5f;
    o.z = (o.z + u.z)*0.5f; o.w = (o.w + u.w)*0.5f;
    return o;
}

// ---------------------------------------------------------------------------
// Kernel 0: zero gDone | gListCnt | gHist.
// ---------------------------------------------------------------------------
__global__ __launch_bounds__(256) void zero_kernel(uint4* __restrict__ p, int n16){
    const int i = blockIdx.x * 256 + threadIdx.x;
    if (i < n16) p[i] = uint4{0u,0u,0u,0u};
}

// ---------------------------------------------------------------------------
// Kernel 1: scores + fused 11-bit histogram + x->out copy. (proven verbatim)
// ---------------------------------------------------------------------------
__global__ __launch_bounds__(256) void scores_hist_copy_kernel(
        const float* __restrict__ x, const float* __restrict__ W_fr,
        const float* __restrict__ b_fr, unsigned* __restrict__ keys,
        unsigned* __restrict__ gHist, float* __restrict__ out, int N, int R)
{
    const int b   = blockIdx.x / K1_CPB;
    const int c   = blockIdx.x % K1_CPB;
    const int rbase = b * R + c * K1_ROWS;
    const int tid = threadIdx.x;
    const int wave = tid >> 6, lane = tid & 63;

    __shared__ unsigned h0[2048], h1[2048];
    for (int i = tid; i < 2048; i += 256){ h0[i] = 0u; h1[i] = 0u; }
    __syncthreads();

    const int f = 4 * (lane & 31);
    const float w00 = W_fr[(f+0)*2+0], w01 = W_fr[(f+0)*2+1];
    const float w10 = W_fr[(f+1)*2+0], w11 = W_fr[(f+1)*2+1];
    const float w20 = W_fr[(f+2)*2+0], w21 = W_fr[(f+2)*2+1];
    const float w30 = W_fr[(f+3)*2+0], w31 = W_fr[(f+3)*2+1];
    const float bf0 = b_fr[0], bf1 = b_fr[1];

    for (int it = 0; it < K1_ROWS/8; ++it){
        const int r0 = rbase + it*8 + wave*2;
        const size_t base = (size_t)r0 * N_IN + 4*lane;
        const float4 xv = *reinterpret_cast<const float4*>(x + base);
        *reinterpret_cast<float4*>(out + base) = xv;       // fused copy
        double p0 = (double)xv.x*w00 + (double)xv.y*w10 + (double)xv.z*w20 + (double)xv.w*w30;
        double p1 = (double)xv.x*w01 + (double)xv.y*w11 + (double)xv.z*w21 + (double)xv.w*w31;
        #pragma unroll
        for (int off = 16; off; off >>= 1){
            p0 += __shfl_xor(p0, off, 32);
            p1 += __shfl_xor(p1, off, 32);
        }
        const unsigned k0 = keyOf((float)(p0 + bf0));
        const unsigned k1 = keyOf((float)(p1 + bf1));
        const int r = r0 + (lane >> 5);
        if ((lane & 31) == 0){ keys[r]     = k0; atomicAdd(&h0[k0 >> 21], 1u); }
        if ((lane & 31) == 1){ keys[N + r] = k1; atomicAdd(&h1[k1 >> 21], 1u); }
    }
    __syncthreads();
    const int slot = c & (HSLOTS-1);
    unsigned* gh0 = gHist + ((size_t)(2*b)   * HSLOTS + slot) * 2048;
    unsigned* gh1 = gHist + ((size_t)(2*b+1) * HSLOTS + slot) * 2048;
    for (int bin = tid; bin < 2048; bin += 256){
        const unsigned s0 = h0[bin], s1 = h1[bin];
        if (s0) atomicAdd(&gh0[bin], s0);
        if (s1) atomicAdd(&gh1[bin], s1);
    }
}

// ---------------------------------------------------------------------------
// Kernel 2: packed candidate collect + per-group last-block refine (R13's
// exact kernel — refcheck-passed; refine overlaps other groups' collect).
// 16 groups x 8 chunks x 1024 threads.
// ---------------------------------------------------------------------------
__global__ __launch_bounds__(1024) void collect_refine_kernel(
        const unsigned* __restrict__ keys, const unsigned* __restrict__ gHist,
        unsigned* __restrict__ gCandCnt, unsigned long long* __restrict__ cand,
        unsigned* __restrict__ gParams, unsigned* __restrict__ gDone,
        int N, int R)
{
    const int g = blockIdx.x >> 3, ch = blockIdx.x & 7;
    const int b = g >> 1, v = g & 1;
    const unsigned* kk = keys + (size_t)v * N + (size_t)b * R;
    const int tid = threadIdx.x, wv = tid >> 6, lane = tid & 63;

    __shared__ unsigned lh[2048];
    __shared__ unsigned coarse[32];
    __shared__ unsigned sB[2];
    __shared__ unsigned wcnt[16];
    __shared__ unsigned sLoc;
    __shared__ unsigned nccs[CCH];
    __shared__ unsigned sOld;

    // ---- (a) redundant per-group threshold ----
    {
        const unsigned* gh = gHist + (size_t)g * HSLOTS * 2048;
        for (int bin = tid; bin < 2048; bin += 1024){
            unsigned ss = 0;
            #pragma unroll
            for (int sl = 0; sl < HSLOTS; ++sl) ss += gh[sl*2048 + bin];
            lh[bin] = ss;
        }
        __syncthreads();
        if (tid < 32){ unsigned ss = 0; for (int j = 0; j < 64; ++j) ss += lh[tid*64+j]; coarse[tid] = ss; }
        __syncthreads();
        if (tid == 0){
            unsigned kneed = KSEL, cum = 0; int cb = 31;
            for (; cb > 0; --cb){ if (cum + coarse[cb] >= kneed) break; cum += coarse[cb]; }
            int bin = cb*64 + 63;
            for (; bin > cb*64; --bin){ if (cum + lh[bin] >= kneed) break; cum += lh[bin]; }
            sB[0] = (unsigned)bin; sB[1] = kneed - cum;
            sLoc = 0u;
        }
        __syncthreads();
    }
    const unsigned B1 = sB[0], kneed1 = sB[1];

    // ---- (b) scan own chunk: packed (key,idx) candidates ----
    {
        unsigned long long* cd = cand + (size_t)g * CAPG + (size_t)ch * 4096;
        const int lo = ch * CSPAN, hi = min(R, lo + CSPAN);
        for (int i0 = lo; i0 < hi; i0 += 1024){
            const int i = i0 + tid;
            const bool pred = (i < hi) && ((kk[i] >> 21) == B1);
            const unsigned u = pred ? kk[i] : 0u;
            unsigned long long m = __ballot(pred);
            if (lane == 0) wcnt[wv] = (unsigned)__popcll(m);
            __syncthreads();
            unsigned pre = sLoc, tot = 0;
            #pragma unroll
            for (int w = 0; w < 16; ++w){ const unsigned cc = wcnt[w]; if (w < wv) pre += cc; tot += cc; }
            if (pred){
                const unsigned p = pre + (unsigned)__popcll(m & ((1ULL << lane) - 1ULL));
                if (p < SUBCAP) cd[p] = ((unsigned long long)u << 32) | (unsigned)i;
            }
            __syncthreads();
            if (tid == 0) sLoc += tot;
            __syncthreads();
        }
        if (tid == 0) gCandCnt[g*CCH + ch] = min(sLoc, SUBCAP);
    }

    // ---- (c) last chunk of this group refines (sequential packed reads) ----
    __threadfence();
    if (tid == 0) sOld = atomicAdd(&gDone[g*16], 1u);
    __syncthreads();
    if (sOld != CCH-1) return;
    __threadfence();   // acquire

    if (tid < CCH) nccs[tid] = gCandCnt[g*CCH + tid];
    __syncthreads();
    const unsigned long long* cd0 = cand + (size_t)g * CAPG;

    // phase B: bits 20..10 (descending)
    for (int i = tid; i < 2048; i += 1024) lh[i] = 0u;
    __syncthreads();
    for (int c2 = 0; c2 < CCH; ++c2){
        const int n = (int)nccs[c2];
        const unsigned long long* cdp = cd0 + (size_t)c2*4096;
        for (int i = tid; i < n; i += 1024)
            atomicAdd(&lh[((unsigned)(cdp[i] >> 32) >> 10) & 0x7FFu], 1u);
    }
    __syncthreads();
    if (tid < 32){ unsigned ss = 0; for (int j = 0; j < 64; ++j) ss += lh[tid*64+j]; coarse[tid] = ss; }
    __syncthreads();
    if (tid == 0){
        unsigned kneed = kneed1, cum = 0; int cb = 31;
        for (; cb > 0; --cb){ if (cum + coarse[cb] >= kneed) break; cum += coarse[cb]; }
        int bin = cb*64 + 63;
        for (; bin > cb*64; --bin){ if (cum + lh[bin] >= kneed) break; cum += lh[bin]; }
        sB[0] = (unsigned)bin; sB[1] = kneed - cum;
    }
    __syncthreads();
    const unsigned B2 = sB[0], kneed2 = sB[1];
    const unsigned top22 = (B1 << 11) | B2;
    __syncthreads();

    // phase C: low 10 bits (descending)
    for (int i = tid; i < 1024; i += 1024) lh[i] = 0u;
    __syncthreads();
    for (int c2 = 0; c2 < CCH; ++c2){
        const int n = (int)nccs[c2];
        const unsigned long long* cdp = cd0 + (size_t)c2*4096;
        for (int i = tid; i < n; i += 1024){
            const unsigned u = (unsigned)(cdp[i] >> 32);
            if ((u >> 10) == top22) atomicAdd(&lh[u & 0x3FFu], 1u);
        }
    }
    __syncthreads();
    if (tid < 32){ unsigned ss = 0; for (int j = 0; j < 32; ++j) ss += lh[tid*32+j]; coarse[tid] = ss; }
    __syncthreads();
    if (tid == 0){
        unsigned kneed = kneed2, cum = 0; int cb = 31;
        for (; cb > 0; --cb){ if (cum + coarse[cb] >= kneed) break; cum += coarse[cb]; }
        int bin = cb*32 + 31;
        for (; bin > cb*32; --bin){ if (cum + lh[bin] >= kneed) break; cum += lh[bin]; }
        sB[0] = (unsigned)bin; sB[1] = kneed - cum;
    }
    __syncthreads();
    const unsigned B3 = sB[0], take_eq = sB[1];
    const unsigned utar = (B1 << 21) | (B2 << 10) | B3;
    __syncthreads();

    // phase T1: idx>>7 among ties (ascending)
    for (int i = tid; i < 1024; i += 1024) lh[i] = 0u;
    __syncthreads();
    for (int c2 = 0; c2 < CCH; ++c2){
        const int n = (int)nccs[c2];
        const unsigned long long* cdp = cd0 + (size_t)c2*4096;
        for (int i = tid; i < n; i += 1024){
            const unsigned long long e = cdp[i];
            if ((unsigned)(e >> 32) == utar) atomicAdd(&lh[((unsigned)e) >> 7], 1u);
        }
    }
    __syncthreads();
    if (tid < 32){ unsigned ss = 0; for (int j = 0; j < 32; ++j) ss += lh[tid*32+j]; coarse[tid] = ss; }
    __syncthreads();
    if (tid == 0){
        unsigned need = take_eq, cum = 0; int cb = 0;
        for (; cb < 31; ++cb){ if (cum + coarse[cb] >= need) break; cum += coarse[cb]; }
        int bin = cb*32;
        for (; bin < cb*32+31; ++bin){ if (cum + lh[bin] >= need) break; cum += lh[bin]; }
        sB[0] = (unsigned)bin; sB[1] = need - cum;
    }
    __syncthreads();
    const unsigned cb7 = sB[0], rem = sB[1];
    __syncthreads();

    // phase T2: low 7 index bits (ascending)
    if (tid < 128) lh[tid] = 0u;
    __syncthreads();
    for (int c2 = 0; c2 < CCH; ++c2){
        const int n = (int)nccs[c2];
        const unsigned long long* cdp = cd0 + (size_t)c2*4096;
        for (int i = tid; i < n; i += 1024){
            const unsigned long long e = cdp[i];
            const unsigned ix = (unsigned)e;
            if ((unsigned)(e >> 32) == utar && (ix >> 7) == cb7) atomicAdd(&lh[ix & 127], 1u);
        }
    }
    __syncthreads();
    if (tid == 0){
        unsigned need = rem, cum = 0; int p = 0;
        for (; p < 127; ++p){ if (cum + lh[p] >= need) break; cum += lh[p]; }
        gParams[g*8+2] = utar;
        gParams[g*8+3] = cb7*128 + (unsigned)p;   // T
    }
}

// ---------------------------------------------------------------------------
// Kernel 3: lean list builder (R12-proven verbatim): 8192 rows/block, pr[8]
// in registers, 2 syncthreads, ONE global atomic per block. No mask.
// ---------------------------------------------------------------------------
__global__ __launch_bounds__(1024) void write_kernel(
        const unsigned* __restrict__ keys, const unsigned* __restrict__ gParams,
        int* __restrict__ lists, unsigned* __restrict__ gListCnt, int N, int R)
{
    const int g = blockIdx.x / WCH, c = blockIdx.x % WCH;
    const int b = g >> 1, v = g & 1;
    const unsigned* kk = keys + (size_t)v * N + (size_t)b * R;
    int* lst = lists + g * KSEL;
    const unsigned utar = gParams[g*8+2];
    const int T = (int)gParams[g*8+3];
    const int tid = threadIdx.x, wave = tid >> 6, lane = tid & 63;
    const int i0 = c * 8192;

    bool pr[8];
    #pragma unroll
    for (int j = 0; j < 8; ++j){
        const int i = i0 + j*1024 + tid;
        const unsigned u = (i < R) ? kk[i] : 0u;
        pr[j] = (i < R) && (u > utar || (u == utar && i <= T));
    }
    __shared__ unsigned wc[8][16];
    __shared__ unsigned ec[8][16];
    __shared__ unsigned sBase;
    #pragma unroll
    for (int j = 0; j < 8; ++j){
        unsigned long long m = __ballot(pr[j]);
        if (lane == 0) wc[j][wave] = (unsigned)__popcll(m);
    }
    __syncthreads();
    if (tid == 0){
        unsigned run = 0;
        for (int j = 0; j < 8; ++j)
            for (int w = 0; w < 16; ++w){ ec[j][w] = run; run += wc[j][w]; }
        sBase = run ? atomicAdd(&gListCnt[g*16], run) : 0u;
    }
    __syncthreads();
    const unsigned base = sBase;
    #pragma unroll
    for (int j = 0; j < 8; ++j){
        unsigned long long m = __ballot(pr[j]);
        if (pr[j])
            lst[base + ec[j][wave] + (unsigned)__popcll(m & ((1ULL << lane) - 1ULL))] = i0 + j*1024 + tid;
    }
}

// ---------------------------------------------------------------------------
// Kernel 4: gather selected rows -> fp64 partial sums. (R12-proven verbatim:
// 16 preloaded indices per thread = deep ILP, 1024 small blocks = max TLP)
// ---------------------------------------------------------------------------
__global__ __launch_bounds__(256) void virt_partial_kernel(
        const float* __restrict__ x, const int* __restrict__ lists,
        double* __restrict__ part, int R)
{
    const int g = blockIdx.x >> 6;
    const int m = blockIdx.x & 63;
    const int b = g >> 1;
    const int tid = threadIdx.x, wave = tid >> 6, lane = tid & 63;
    const int* lst = lists + g * KSEL + m * 64;
    int idxs[16];
    #pragma unroll
    for (int e = 0; e < 16; ++e) idxs[e] = lst[e*4 + wave];
    double a0 = 0.0, a1 = 0.0;
    #pragma unroll
    for (int e = 0; e < 16; ++e){
        const float2 xv = *reinterpret_cast<const float2*>(
            x + ((size_t)b * R + idxs[e]) * N_IN + 2*lane);
        a0 += xv.x; a1 += xv.y;
    }
    __shared__ double pp[4][128];
    pp[wave][2*lane]   = a0;
    pp[wave][2*lane+1] = a1;
    __syncthreads();
    if (tid < 128){
        double s = pp[0][tid] + pp[1][tid] + pp[2][tid] + pp[3][tid];
        part[(size_t)(g*VCH + m) * N_IN + tid] = s;
    }
}

// ---------------------------------------------------------------------------
// Kernel 5: redundant fp64 MLP per block + sparse blend with key-probe dedup.
// 16 groups x 16 slices x 256 threads. (R12-proven verbatim)
// ---------------------------------------------------------------------------
__global__ __launch_bounds__(256) void update_mlp_kernel(
        const float* __restrict__ x, const unsigned* __restrict__ keys,
        const int* __restrict__ lists, const double* __restrict__ part,
        const unsigned* __restrict__ gParams,
        const float* __restrict__ W1, const float* __restrict__ b1,
        const float* __restrict__ W2, const float* __restrict__ b2,
        float* __restrict__ out, int N, int R)
{
    const int g = blockIdx.x >> 4, sl = blockIdx.x & (USLICE-1);
    const int b = g >> 1, v = g & 1;
    const int tid = threadIdx.x;

    __shared__ __align__(16) float inv[DD];
    __shared__ __align__(16) float h1s[DD];
    __shared__ __align__(16) float uu[DD];

    {
        const int g2 = b*2 + (tid >> 7);
        const int fcol = tid & 127;
        double ssum = 0.0;
        for (int cc = 0; cc < VCH; ++cc) ssum += part[((size_t)g2 * VCH + cc) * N_IN + fcol];
        inv[tid] = (float)(ssum / (double)KSEL);
    }
    __syncthreads();
    {
        double q0=0, q1=0, q2=0, q3=0;
        for (int i = 0; i < DD; i += 4){
            q0 += (double)inv[i+0] * (double)W1[(i+0)*DD + tid];
            q1 += (double)inv[i+1] * (double)W1[(i+1)*DD + tid];
            q2 += (double)inv[i+2] * (double)W1[(i+2)*DD + tid];
            q3 += (double)inv[i+3] * (double)W1[(i+3)*DD + tid];
        }
        h1s[tid] = fmaxf((float)(((q0+q1)+(q2+q3)) + (double)b1[tid]), 0.0f);
    }
    __syncthreads();
    {
        double q0=0, q1=0, q2=0, q3=0;
        for (int i = 0; i < DD; i += 4){
            q0 += (double)h1s[i+0] * (double)W2[(i+0)*DD + tid];
            q1 += (double)h1s[i+1] * (double)W2[(i+1)*DD + tid];
            q2 += (double)h1s[i+2] * (double)W2[(i+2)*DD + tid];
            q3 += (double)h1s[i+3] * (double)W2[(i+3)*DD + tid];
        }
        uu[tid] = (float)(((q0+q1)+(q2+q3)) + (double)b2[tid]);
    }
    __syncthreads();

    const int wave = tid >> 6, lane = tid & 63;
    const int half = lane >> 5;
    const int c4 = (lane & 31) * 4;
    const int* lst = lists + g * KSEL + sl * (KSEL/USLICE);
    const unsigned* k0p = keys + (size_t)b * R;
    const unsigned* k1p = keys + (size_t)N + (size_t)b * R;
    const unsigned utar0 = gParams[(b*2+0)*8+2]; const int T0  = (int)gParams[(b*2+0)*8+3];
    const unsigned utar1 = gParams[(b*2+1)*8+2]; const int T1v = (int)gParams[(b*2+1)*8+3];
    const float4 u0 = *reinterpret_cast<const float4*>(&uu[c4]);
    const float4 u1 = *reinterpret_cast<const float4*>(&uu[128 + c4]);
    const size_t rowBase = (size_t)b * R;

    for (int e = wave*2 + half; e < KSEL/USLICE; e += 8){
        const int row = lst[e];
        if (v == 1){
            const unsigned uk0 = k0p[row];
            if (uk0 > utar0 || (uk0 == utar0 && row <= T0)) continue;  // v0 pass handles
        }
        const size_t base = (rowBase + row) * N_IN + c4;
        float4 o = *reinterpret_cast<const float4*>(x + base);
        if (v == 0){
            o = blend4(o, u0);
            const unsigned uk1 = k1p[row];
            if (uk1 > utar1 || (uk1 == utar1 && row <= T1v)) o = blend4(o, u1);
        } else {
            o = blend4(o, u1);
        }
        *reinterpret_cast<float4*>(out + base) = o;
    }
}

extern "C" void kernel_launch(void* const* d_in, const int* in_sizes, int n_in_cnt,
                              void* d_out, int out_size, void* d_ws, size_t ws_size,
                              hipStream_t stream)
{
    const float* x    = (const float*)d_in[0];
    const float* W_fr = (const float*)d_in[1];
    const float* b_fr = (const float*)d_in[2];
    const float* W1   = (const float*)d_in[3];
    const float* b1   = (const float*)d_in[4];
    const float* W2   = (const float*)d_in[5];
    const float* b2   = (const float*)d_in[6];
    float* out = (float*)d_out;
    const int N = in_sizes[0] / N_IN;   // 800000
    const int R = N / NBATCH;           // 100000

    char* ws = (char*)d_ws;
    size_t off = 0;
    auto alloc = [&](size_t bytes) -> void* {
        void* p = ws + off;
        off = (off + bytes + 255) & ~(size_t)255;
        return p;
    };
    int*                lists   = (int*)               alloc((size_t)NGROUP * KSEL * 4);
    double*             part    = (double*)            alloc((size_t)NGROUP * VCH * N_IN * 8);
    unsigned long long* cand    = (unsigned long long*)alloc((size_t)NGROUP * CAPG * 8);
    unsigned*           keys    = (unsigned*)          alloc((size_t)2 * N * 4);
    unsigned*           gParams = (unsigned*)          alloc((size_t)NGROUP * 8 * 4);
    unsigned*           gCandCnt= (unsigned*)          alloc((size_t)NGROUP * CCH * 4);

    // zeroed region: gDone(16x16) | gListCnt(16x16) | gHist(16 x HSLOTS x 2048)
    const size_t zrUints = 16*16 + 16*16 + (size_t)NGROUP * HSLOTS * 2048;
    unsigned* zr = (unsigned*)alloc(zrUints * 4);
    unsigned* gDone    = zr;
    unsigned* gListCnt = zr + 16*16;
    unsigned* gHist    = zr + 16*16 + 16*16;

    const int n16 = (int)((zrUints * 4 + 15) / 16);
    zero_kernel<<<dim3((n16 + 255)/256), dim3(256), 0, stream>>>((uint4*)zr, n16);
    scores_hist_copy_kernel<<<dim3(NBATCH*K1_CPB), dim3(256), 0, stream>>>(
        x, W_fr, b_fr, keys, gHist, out, N, R);
    collect_refine_kernel<<<dim3(NGROUP*CCH), dim3(1024), 0, stream>>>(
        keys, gHist, gCandCnt, cand, gParams, gDone, N, R);
    write_kernel<<<dim3(NGROUP*WCH), dim3(1024), 0, stream>>>(
        keys, gParams, lists, gListCnt, N, R);
    virt_partial_kernel<<<dim3(NGROUP*VCH), dim3(256), 0, stream>>>(
        x, lists, part, R);
    update_mlp_kernel<<<dim3(NGROUP*USLICE), dim3(256), 0, stream>>>(
        x, keys, lists, part, gParams, W1, b1, W2, b2, out, N, R);
}

// Round 15
// 299.864 us; speedup vs baseline: 1.1493x; 1.1302x over previous
//
#include <hip/hip_runtime.h>

#define N_IN   128
#define DD     256
#define KSEL   4096
#define NBATCH 8
#define NGROUP 16
#define HSLOTS 4
#define K1_CPB 250
#define K1_ROWS 400
#define CCH    8            // collect chunks per group
#define CSPAN  12500        // RR / CCH
#define SUBCAP 4096u        // packed-candidate cap per (group,chunk)
#define CAPG   (CCH*4096)
#define WCH    13           // write chunks per group (13*8192 >= 100000)
#define VCH    64           // virt_partial chunks per group (part slots)
#define USLICE 16           // update slices per group

__device__ __forceinline__ unsigned keyOf(float s){
    unsigned b = __float_as_uint(s);
    return (b & 0x80000000u) ? ~b : (b | 0x80000000u);
}

__device__ __forceinline__ float4 blend4(float4 o, float4 u){
    o.x = (o.x + u.x)*0.5f; o.y = (o.y + u.y)*0.5f;
    o.z = (o.z + u.z)*0.5f; o.w = (o.w + u.w)*0.5f;
    return o;
}

// ---------------------------------------------------------------------------
// Kernel 0: zero gListCnt + gHist.
// ---------------------------------------------------------------------------
__global__ __launch_bounds__(256) void zero_kernel(uint4* __restrict__ p, int n16){
    const int i = blockIdx.x * 256 + threadIdx.x;
    if (i < n16) p[i] = uint4{0u,0u,0u,0u};
}

// ---------------------------------------------------------------------------
// Kernel 1: scores + fused 11-bit histogram + x->out copy.
// ---------------------------------------------------------------------------
__global__ __launch_bounds__(256) void scores_hist_copy_kernel(
        const float* __restrict__ x, const float* __restrict__ W_fr,
        const float* __restrict__ b_fr, unsigned* __restrict__ keys,
        unsigned* __restrict__ gHist, float* __restrict__ out, int N, int R)
{
    const int b   = blockIdx.x / K1_CPB;
    const int c   = blockIdx.x % K1_CPB;
    const int rbase = b * R + c * K1_ROWS;
    const int tid = threadIdx.x;
    const int wave = tid >> 6, lane = tid & 63;

    __shared__ unsigned h0[2048], h1[2048];
    for (int i = tid; i < 2048; i += 256){ h0[i] = 0u; h1[i] = 0u; }
    __syncthreads();

    const int f = 4 * (lane & 31);
    const float w00 = W_fr[(f+0)*2+0], w01 = W_fr[(f+0)*2+1];
    const float w10 = W_fr[(f+1)*2+0], w11 = W_fr[(f+1)*2+1];
    const float w20 = W_fr[(f+2)*2+0], w21 = W_fr[(f+2)*2+1];
    const float w30 = W_fr[(f+3)*2+0], w31 = W_fr[(f+3)*2+1];
    const float bf0 = b_fr[0], bf1 = b_fr[1];

    for (int it = 0; it < K1_ROWS/8; ++it){
        const int r0 = rbase + it*8 + wave*2;
        const size_t base = (size_t)r0 * N_IN + 4*lane;
        const float4 xv = *reinterpret_cast<const float4*>(x + base);
        *reinterpret_cast<float4*>(out + base) = xv;       // fused copy
        double p0 = (double)xv.x*w00 + (double)xv.y*w10 + (double)xv.z*w20 + (double)xv.w*w30;
        double p1 = (double)xv.x*w01 + (double)xv.y*w11 + (double)xv.z*w21 + (double)xv.w*w31;
        #pragma unroll
        for (int off = 16; off; off >>= 1){
            p0 += __shfl_xor(p0, off, 32);
            p1 += __shfl_xor(p1, off, 32);
        }
        const unsigned k0 = keyOf((float)(p0 + bf0));
        const unsigned k1 = keyOf((float)(p1 + bf1));
        const int r = r0 + (lane >> 5);
        if ((lane & 31) == 0){ keys[r]     = k0; atomicAdd(&h0[k0 >> 21], 1u); }
        if ((lane & 31) == 1){ keys[N + r] = k1; atomicAdd(&h1[k1 >> 21], 1u); }
    }
    __syncthreads();
    const int slot = c & (HSLOTS-1);
    unsigned* gh0 = gHist + ((size_t)(2*b)   * HSLOTS + slot) * 2048;
    unsigned* gh1 = gHist + ((size_t)(2*b+1) * HSLOTS + slot) * 2048;
    for (int bin = tid; bin < 2048; bin += 256){
        const unsigned s0 = h0[bin], s1 = h1[bin];
        if (s0) atomicAdd(&gh0[bin], s0);
        if (s1) atomicAdd(&gh1[bin], s1);
    }
}

// ---------------------------------------------------------------------------
// Kernel 2: redundant threshold + packed (key,idx) candidate collect.
// 16 groups x 8 chunks x 1024 threads. Uniform exit, zero global atomics.
// ---------------------------------------------------------------------------
__global__ __launch_bounds__(1024) void collect_kernel(
        const unsigned* __restrict__ keys, const unsigned* __restrict__ gHist,
        unsigned* __restrict__ gCandCnt, unsigned long long* __restrict__ cand,
        int N, int R)
{
    const int g = blockIdx.x >> 3, ch = blockIdx.x & 7;
    const int b = g >> 1, v = g & 1;
    const unsigned* kk = keys + (size_t)v * N + (size_t)b * R;
    const int tid = threadIdx.x, wv = tid >> 6, lane = tid & 63;

    __shared__ unsigned lh[2048];
    __shared__ unsigned coarse[32];
    __shared__ unsigned sB1;
    __shared__ unsigned wcnt[16];
    __shared__ unsigned sLoc;

    // redundant per-group threshold
    {
        const unsigned* gh = gHist + (size_t)g * HSLOTS * 2048;
        for (int bin = tid; bin < 2048; bin += 1024){
            unsigned ss = 0;
            #pragma unroll
            for (int sl = 0; sl < HSLOTS; ++sl) ss += gh[sl*2048 + bin];
            lh[bin] = ss;
        }
        __syncthreads();
        if (tid < 32){ unsigned ss = 0; for (int j = 0; j < 64; ++j) ss += lh[tid*64+j]; coarse[tid] = ss; }
        __syncthreads();
        if (tid == 0){
            unsigned kneed = KSEL, cum = 0; int cb = 31;
            for (; cb > 0; --cb){ if (cum + coarse[cb] >= kneed) break; cum += coarse[cb]; }
            int bin = cb*64 + 63;
            for (; bin > cb*64; --bin){ if (cum + lh[bin] >= kneed) break; cum += lh[bin]; }
            sB1 = (unsigned)bin; sLoc = 0u;
        }
        __syncthreads();
    }
    const unsigned B1 = sB1;

    unsigned long long* cd = cand + (size_t)g * CAPG + (size_t)ch * 4096;
    const int lo = ch * CSPAN, hi = min(R, lo + CSPAN);
    for (int i0 = lo; i0 < hi; i0 += 1024){
        const int i = i0 + tid;
        const bool pred = (i < hi) && ((kk[i] >> 21) == B1);
        const unsigned u = pred ? kk[i] : 0u;
        unsigned long long m = __ballot(pred);
        if (lane == 0) wcnt[wv] = (unsigned)__popcll(m);
        __syncthreads();
        unsigned pre = sLoc, tot = 0;
        #pragma unroll
        for (int w = 0; w < 16; ++w){ const unsigned cc = wcnt[w]; if (w < wv) pre += cc; tot += cc; }
        if (pred){
            const unsigned p = pre + (unsigned)__popcll(m & ((1ULL << lane) - 1ULL));
            if (p < SUBCAP) cd[p] = ((unsigned long long)u << 32) | (unsigned)i;
        }
        __syncthreads();
        if (tid == 0) sLoc += tot;
        __syncthreads();
    }
    if (tid == 0) gCandCnt[g*CCH + ch] = min(sLoc, SUBCAP);
}

// ---------------------------------------------------------------------------
// Kernel 3: per-group refine over SEQUENTIAL packed candidates -> utar, T.
// 16 blocks x 1024 threads.
// ---------------------------------------------------------------------------
__global__ __launch_bounds__(1024) void select2_kernel(
        const unsigned* __restrict__ gHist, const unsigned long long* __restrict__ cand,
        const unsigned* __restrict__ gCandCnt, unsigned* __restrict__ gParams)
{
    const int g = blockIdx.x;
    const int tid = threadIdx.x;

    __shared__ unsigned lh[2048];
    __shared__ unsigned coarse[32];
    __shared__ unsigned sB[2];
    __shared__ unsigned nccs[CCH];

    // threshold (B1, kneed1) from gHist — identical code to collect => same B1
    {
        const unsigned* gh = gHist + (size_t)g * HSLOTS * 2048;
        for (int bin = tid; bin < 2048; bin += 1024){
            unsigned ss = 0;
            #pragma unroll
            for (int sl = 0; sl < HSLOTS; ++sl) ss += gh[sl*2048 + bin];
            lh[bin] = ss;
        }
        __syncthreads();
        if (tid < 32){ unsigned ss = 0; for (int j = 0; j < 64; ++j) ss += lh[tid*64+j]; coarse[tid] = ss; }
        __syncthreads();
        if (tid == 0){
            unsigned kneed = KSEL, cum = 0; int cb = 31;
            for (; cb > 0; --cb){ if (cum + coarse[cb] >= kneed) break; cum += coarse[cb]; }
            int bin = cb*64 + 63;
            for (; bin > cb*64; --bin){ if (cum + lh[bin] >= kneed) break; cum += lh[bin]; }
            sB[0] = (unsigned)bin; sB[1] = kneed - cum;
        }
        __syncthreads();
    }
    const unsigned B1 = sB[0], kneed1 = sB[1];
    if (tid < CCH) nccs[tid] = gCandCnt[g*CCH + tid];
    __syncthreads();
    const unsigned long long* cd0 = cand + (size_t)g * CAPG;

    // phase B: bits 20..10 (descending)
    for (int i = tid; i < 2048; i += 1024) lh[i] = 0u;
    __syncthreads();
    for (int c2 = 0; c2 < CCH; ++c2){
        const int n = (int)nccs[c2];
        const unsigned long long* cdp = cd0 + (size_t)c2*4096;
        for (int i = tid; i < n; i += 1024)
            atomicAdd(&lh[((unsigned)(cdp[i] >> 32) >> 10) & 0x7FFu], 1u);
    }
    __syncthreads();
    if (tid < 32){ unsigned ss = 0; for (int j = 0; j < 64; ++j) ss += lh[tid*64+j]; coarse[tid] = ss; }
    __syncthreads();
    if (tid == 0){
        unsigned kneed = kneed1, cum = 0; int cb = 31;
        for (; cb > 0; --cb){ if (cum + coarse[cb] >= kneed) break; cum += coarse[cb]; }
        int bin = cb*64 + 63;
        for (; bin > cb*64; --bin){ if (cum + lh[bin] >= kneed) break; cum += lh[bin]; }
        sB[0] = (unsigned)bin; sB[1] = kneed - cum;
    }
    __syncthreads();
    const unsigned B2 = sB[0], kneed2 = sB[1];
    const unsigned top22 = (B1 << 11) | B2;
    __syncthreads();

    // phase C: low 10 bits (descending)
    for (int i = tid; i < 1024; i += 1024) lh[i] = 0u;
    __syncthreads();
    for (int c2 = 0; c2 < CCH; ++c2){
        const int n = (int)nccs[c2];
        const unsigned long long* cdp = cd0 + (size_t)c2*4096;
        for (int i = tid; i < n; i += 1024){
            const unsigned u = (unsigned)(cdp[i] >> 32);
            if ((u >> 10) == top22) atomicAdd(&lh[u & 0x3FFu], 1u);
        }
    }
    __syncthreads();
    if (tid < 32){ unsigned ss = 0; for (int j = 0; j < 32; ++j) ss += lh[tid*32+j]; coarse[tid] = ss; }
    __syncthreads();
    if (tid == 0){
        unsigned kneed = kneed2, cum = 0; int cb = 31;
        for (; cb > 0; --cb){ if (cum + coarse[cb] >= kneed) break; cum += coarse[cb]; }
        int bin = cb*32 + 31;
        for (; bin > cb*32; --bin){ if (cum + lh[bin] >= kneed) break; cum += lh[bin]; }
        sB[0] = (unsigned)bin; sB[1] = kneed - cum;
    }
    __syncthreads();
    const unsigned B3 = sB[0], take_eq = sB[1];
    const unsigned utar = (B1 << 21) | (B2 << 10) | B3;
    __syncthreads();

    // phase T1: idx>>7 among ties (ascending)
    for (int i = tid; i < 1024; i += 1024) lh[i] = 0u;
    __syncthreads();
    for (int c2 = 0; c2 < CCH; ++c2){
        const int n = (int)nccs[c2];
        const unsigned long long* cdp = cd0 + (size_t)c2*4096;
        for (int i = tid; i < n; i += 1024){
            const unsigned long long e = cdp[i];
            if ((unsigned)(e >> 32) == utar) atomicAdd(&lh[((unsigned)e) >> 7], 1u);
        }
    }
    __syncthreads();
    if (tid < 32){ unsigned ss = 0; for (int j = 0; j < 32; ++j) ss += lh[tid*32+j]; coarse[tid] = ss; }
    __syncthreads();
    if (tid == 0){
        unsigned need = take_eq, cum = 0; int cb = 0;
        for (; cb < 31; ++cb){ if (cum + coarse[cb] >= need) break; cum += coarse[cb]; }
        int bin = cb*32;
        for (; bin < cb*32+31; ++bin){ if (cum + lh[bin] >= need) break; cum += lh[bin]; }
        sB[0] = (unsigned)bin; sB[1] = need - cum;
    }
    __syncthreads();
    const unsigned cb7 = sB[0], rem = sB[1];
    __syncthreads();

    // phase T2: low 7 index bits (ascending)
    if (tid < 128) lh[tid] = 0u;
    __syncthreads();
    for (int c2 = 0; c2 < CCH; ++c2){
        const int n = (int)nccs[c2];
        const unsigned long long* cdp = cd0 + (size_t)c2*4096;
        for (int i = tid; i < n; i += 1024){
            const unsigned long long e = cdp[i];
            const unsigned ix = (unsigned)e;
            if ((unsigned)(e >> 32) == utar && (ix >> 7) == cb7) atomicAdd(&lh[ix & 127], 1u);
        }
    }
    __syncthreads();
    if (tid == 0){
        unsigned need = rem, cum = 0; int p = 0;
        for (; p < 127; ++p){ if (cum + lh[p] >= need) break; cum += lh[p]; }
        gParams[g*8+2] = utar;
        gParams[g*8+3] = cb7*128 + (unsigned)p;   // T
    }
}

// ---------------------------------------------------------------------------
// Kernel 4: lean list builder: 8192 rows/block, pr[8] in registers,
// 2 syncthreads, ONE global atomic per block. No mask.
// ---------------------------------------------------------------------------
__global__ __launch_bounds__(1024) void write_kernel(
        const unsigned* __restrict__ keys, const unsigned* __restrict__ gParams,
        int* __restrict__ lists, unsigned* __restrict__ gListCnt, int N, int R)
{
    const int g = blockIdx.x / WCH, c = blockIdx.x % WCH;
    const int b = g >> 1, v = g & 1;
    const unsigned* kk = keys + (size_t)v * N + (size_t)b * R;
    int* lst = lists + g * KSEL;
    const unsigned utar = gParams[g*8+2];
    const int T = (int)gParams[g*8+3];
    const int tid = threadIdx.x, wave = tid >> 6, lane = tid & 63;
    const int i0 = c * 8192;

    bool pr[8];
    #pragma unroll
    for (int j = 0; j < 8; ++j){
        const int i = i0 + j*1024 + tid;
        const unsigned u = (i < R) ? kk[i] : 0u;
        pr[j] = (i < R) && (u > utar || (u == utar && i <= T));
    }
    __shared__ unsigned wc[8][16];
    __shared__ unsigned ec[8][16];
    __shared__ unsigned sBase;
    #pragma unroll
    for (int j = 0; j < 8; ++j){
        unsigned long long m = __ballot(pr[j]);
        if (lane == 0) wc[j][wave] = (unsigned)__popcll(m);
    }
    __syncthreads();
    if (tid == 0){
        unsigned run = 0;
        for (int j = 0; j < 8; ++j)
            for (int w = 0; w < 16; ++w){ ec[j][w] = run; run += wc[j][w]; }
        sBase = run ? atomicAdd(&gListCnt[g*16], run) : 0u;
    }
    __syncthreads();
    const unsigned base = sBase;
    #pragma unroll
    for (int j = 0; j < 8; ++j){
        unsigned long long m = __ballot(pr[j]);
        if (pr[j])
            lst[base + ec[j][wave] + (unsigned)__popcll(m & ((1ULL << lane) - 1ULL))] = i0 + j*1024 + tid;
    }
}

// ---------------------------------------------------------------------------
// Kernel 5: gather selected rows -> fp64 partial sums. (deep ILP: 16
// preloaded indices/thread; 1024 small blocks = max TLP)
// ---------------------------------------------------------------------------
__global__ __launch_bounds__(256) void virt_partial_kernel(
        const float* __restrict__ x, const int* __restrict__ lists,
        double* __restrict__ part, int R)
{
    const int g = blockIdx.x >> 6;
    const int m = blockIdx.x & 63;
    const int b = g >> 1;
    const int tid = threadIdx.x, wave = tid >> 6, lane = tid & 63;
    const int* lst = lists + g * KSEL + m * 64;
    int idxs[16];
    #pragma unroll
    for (int e = 0; e < 16; ++e) idxs[e] = lst[e*4 + wave];
    double a0 = 0.0, a1 = 0.0;
    #pragma unroll
    for (int e = 0; e < 16; ++e){
        const float2 xv = *reinterpret_cast<const float2*>(
            x + ((size_t)b * R + idxs[e]) * N_IN + 2*lane);
        a0 += xv.x; a1 += xv.y;
    }
    __shared__ double pp[4][128];
    pp[wave][2*lane]   = a0;
    pp[wave][2*lane+1] = a1;
    __syncthreads();
    if (tid < 128){
        double s = pp[0][tid] + pp[1][tid] + pp[2][tid] + pp[3][tid];
        part[(size_t)(g*VCH + m) * N_IN + tid] = s;
    }
}

// ---------------------------------------------------------------------------
// Kernel 6: redundant fp64 MLP per block + sparse blend with key-probe dedup.
// 16 groups x 16 slices x 256 threads.
// ---------------------------------------------------------------------------
__global__ __launch_bounds__(256) void update_mlp_kernel(
        const float* __restrict__ x, const unsigned* __restrict__ keys,
        const int* __restrict__ lists, const double* __restrict__ part,
        const unsigned* __restrict__ gParams,
        const float* __restrict__ W1, const float* __restrict__ b1,
        const float* __restrict__ W2, const float* __restrict__ b2,
        float* __restrict__ out, int N, int R)
{
    const int g = blockIdx.x >> 4, sl = blockIdx.x & (USLICE-1);
    const int b = g >> 1, v = g & 1;
    const int tid = threadIdx.x;

    __shared__ __align__(16) float inv[DD];
    __shared__ __align__(16) float h1s[DD];
    __shared__ __align__(16) float uu[DD];

    {
        const int g2 = b*2 + (tid >> 7);
        const int fcol = tid & 127;
        double ssum = 0.0;
        for (int cc = 0; cc < VCH; ++cc) ssum += part[((size_t)g2 * VCH + cc) * N_IN + fcol];
        inv[tid] = (float)(ssum / (double)KSEL);
    }
    __syncthreads();
    {
        double q0=0, q1=0, q2=0, q3=0;
        for (int i = 0; i < DD; i += 4){
            q0 += (double)inv[i+0] * (double)W1[(i+0)*DD + tid];
            q1 += (double)inv[i+1] * (double)W1[(i+1)*DD + tid];
            q2 += (double)inv[i+2] * (double)W1[(i+2)*DD + tid];
            q3 += (double)inv[i+3] * (double)W1[(i+3)*DD + tid];
        }
        h1s[tid] = fmaxf((float)(((q0+q1)+(q2+q3)) + (double)b1[tid]), 0.0f);
    }
    __syncthreads();
    {
        double q0=0, q1=0, q2=0, q3=0;
        for (int i = 0; i < DD; i += 4){
            q0 += (double)h1s[i+0] * (double)W2[(i+0)*DD + tid];
            q1 += (double)h1s[i+1] * (double)W2[(i+1)*DD + tid];
            q2 += (double)h1s[i+2] * (double)W2[(i+2)*DD + tid];
            q3 += (double)h1s[i+3] * (double)W2[(i+3)*DD + tid];
        }
        uu[tid] = (float)(((q0+q1)+(q2+q3)) + (double)b2[tid]);
    }
    __syncthreads();

    const int wave = tid >> 6, lane = tid & 63;
    const int half = lane >> 5;
    const int c4 = (lane & 31) * 4;
    const int* lst = lists + g * KSEL + sl * (KSEL/USLICE);
    const unsigned* k0p = keys + (size_t)b * R;
    const unsigned* k1p = keys + (size_t)N + (size_t)b * R;
    const unsigned utar0 = gParams[(b*2+0)*8+2]; const int T0  = (int)gParams[(b*2+0)*8+3];
    const unsigned utar1 = gParams[(b*2+1)*8+2]; const int T1v = (int)gParams[(b*2+1)*8+3];
    const float4 u0 = *reinterpret_cast<const float4*>(&uu[c4]);
    const float4 u1 = *reinterpret_cast<const float4*>(&uu[128 + c4]);
    const size_t rowBase = (size_t)b * R;

    for (int e = wave*2 + half; e < KSEL/USLICE; e += 8){
        const int row = lst[e];
        if (v == 1){
            const unsigned uk0 = k0p[row];
            if (uk0 > utar0 || (uk0 == utar0 && row <= T0)) continue;  // v0 pass handles
        }
        const size_t base = (rowBase + row) * N_IN + c4;
        float4 o = *reinterpret_cast<const float4*>(x + base);
        if (v == 0){
            o = blend4(o, u0);
            const unsigned uk1 = k1p[row];
            if (uk1 > utar1 || (uk1 == utar1 && row <= T1v)) o = blend4(o, u1);
        } else {
            o = blend4(o, u1);
        }
        *reinterpret_cast<float4*>(out + base) = o;
    }
}

extern "C" void kernel_launch(void* const* d_in, const int* in_sizes, int n_in_cnt,
                              void* d_out, int out_size, void* d_ws, size_t ws_size,
                              hipStream_t stream)
{
    const float* x    = (const float*)d_in[0];
    const float* W_fr = (const float*)d_in[1];
    const float* b_fr = (const float*)d_in[2];
    const float* W1   = (const float*)d_in[3];
    const float* b1   = (const float*)d_in[4];
    const float* W2   = (const float*)d_in[5];
    const float* b2   = (const float*)d_in[6];
    float* out = (float*)d_out;
    const int N = in_sizes[0] / N_IN;   // 800000
    const int R = N / NBATCH;           // 100000

    char* ws = (char*)d_ws;
    size_t off = 0;
    auto alloc = [&](size_t bytes) -> void* {
        void* p = ws + off;
        off = (off + bytes + 255) & ~(size_t)255;
        return p;
    };
    int*                lists   = (int*)               alloc((size_t)NGROUP * KSEL * 4);
    double*             part    = (double*)            alloc((size_t)NGROUP * VCH * N_IN * 8);
    unsigned long long* cand    = (unsigned long long*)alloc((size_t)NGROUP * CAPG * 8);
    unsigned*           keys    = (unsigned*)          alloc((size_t)2 * N * 4);
    unsigned*           gParams = (unsigned*)          alloc((size_t)NGROUP * 8 * 4);
    unsigned*           gCandCnt= (unsigned*)          alloc((size_t)NGROUP * CCH * 4);

    // zeroed region: gListCnt(16x16) | gHist(16 x HSLOTS x 2048)
    const size_t zrUints = 16*16 + (size_t)NGROUP * HSLOTS * 2048;
    unsigned* zr = (unsigned*)alloc(zrUints * 4);
    unsigned* gListCnt = zr;
    unsigned* gHist    = zr + 16*16;

    const int n16 = (int)((zrUints * 4 + 15) / 16);
    zero_kernel<<<dim3((n16 + 255)/256), dim3(256), 0, stream>>>((uint4*)zr, n16);
    scores_hist_copy_kernel<<<dim3(NBATCH*K1_CPB), dim3(256), 0, stream>>>(
        x, W_fr, b_fr, keys, gHist, out, N, R);
    collect_kernel<<<dim3(NGROUP*CCH), dim3(1024), 0, stream>>>(
        keys, gHist, gCandCnt, cand, N, R);
    select2_kernel<<<dim3(NGROUP), dim3(1024), 0, stream>>>(
        gHist, cand, gCandCnt, gParams);
    write_kernel<<<dim3(NGROUP*WCH), dim3(1024), 0, stream>>>(
        keys, gParams, lists, gListCnt, N, R);
    virt_partial_kernel<<<dim3(NGROUP*VCH), dim3(256), 0, stream>>>(
        x, lists, part, R);
    update_mlp_kernel<<<dim3(NGROUP*USLICE), dim3(256), 0, stream>>>(
        x, keys, lists, part, gParams, W1, b1, W2, b2, out, N, R);
}